// Round 12
// baseline (457.901 us; speedup 1.0000x reference)
//
#include <hip/hip_runtime.h>
#include <hip/hip_bf16.h>
#include <hip/hip_fp16.h>
#include <math.h>

// Problem constants
#define NPTS 65536
#define DIM  256
#define KC   512

// som_main geometry
#define BM    64                  // points per block
#define NBLK  (NPTS / BM)         // 1024 blocks
#define XSTR  264                 // x LDS row stride in halfs (528 B, 16B-aligned)
#define EPS   0.1f                // coarse hi-only dist err sigma ~0.013 -> 7+ sigma margin

// d_out layout (floats): [0]=loss, [1..1+16777216)=quantized, [16777217]=perplexity,
// [16777218..+65536)=enc_idx (as float)
#define QOFF  1
#define PIDX  16777217
#define EOFF  16777218

// d_ws layout:
//   wfh  _Float16[131072]  @ 0        (256 KB)  w hi, MFMA fragment order
//   wsq  float[512]        @ 262144
//   g    float[512]        @ 264192
//   hist int[512]          @ 266240
//   mse  double            @ 268288
// fragment order: off(c,k) = ((c>>4)*8 + (k>>5))*512 + ((k>>3)&3)*128 + (c&15)*8 + (k&7)

typedef _Float16 h8    __attribute__((ext_vector_type(8)));
typedef float    f32x4 __attribute__((ext_vector_type(4)));

// merge top-2 set with another top-2 set; first-index tie-break on best (r5-verified)
__device__ inline void merge_top2(float& b1, int& i1, float& b2, int& i2,
                                  float ob1, int oi1, float ob2, int oi2) {
    bool ow = (ob1 < b1) || (ob1 == b1 && oi1 < i1);
    float lb = ow ? b1 : ob1; int li = ow ? i1 : oi1;
    if (ow) { b1 = ob1; i1 = oi1; }
    float c2 = b2; int ci = i2;
    if (ob2 < c2 || (ob2 == c2 && oi2 < ci)) { c2 = ob2; ci = oi2; }
    if (lb  < c2 || (lb  == c2 && li  < ci)) { c2 = lb;  ci = li;  }
    b2 = c2; i2 = ci;
}

// ---------------- prep: wsq (exact r3 order) + hi-f16 fragment conversion ----------------
__global__ __launch_bounds__(256) void som_prep(const float* __restrict__ w,
                                                _Float16* __restrict__ wfh,
                                                float* __restrict__ wsq,
                                                int* __restrict__ hist,
                                                double* __restrict__ mse_acc)
{
    int c = blockIdx.x * 256 + threadIdx.x;   // code row; grid = 2
    const float4* r = reinterpret_cast<const float4*>(w + (size_t)c * DIM);
    float s0 = 0.f, s1 = 0.f, s2 = 0.f, s3 = 0.f;
    #pragma unroll 4
    for (int g = 0; g < 32; ++g) {
        float4 a = r[g * 2], b = r[g * 2 + 1];
        s0 = fmaf(a.x, a.x, s0); s1 = fmaf(a.y, a.y, s1);
        s2 = fmaf(a.z, a.z, s2); s3 = fmaf(a.w, a.w, s3);
        s0 = fmaf(b.x, b.x, s0); s1 = fmaf(b.y, b.y, s1);
        s2 = fmaf(b.z, b.z, s2); s3 = fmaf(b.w, b.w, s3);
        h8 hv;
        hv[0] = (_Float16)a.x; hv[1] = (_Float16)a.y;
        hv[2] = (_Float16)a.z; hv[3] = (_Float16)a.w;
        hv[4] = (_Float16)b.x; hv[5] = (_Float16)b.y;
        hv[6] = (_Float16)b.z; hv[7] = (_Float16)b.w;
        size_t off = (((size_t)((c >> 4) * 8 + (g >> 2))) * 4 + (g & 3)) * 128 + (c & 15) * 8;
        *reinterpret_cast<h8*>(wfh + off) = hv;
    }
    wsq[c] = (s0 + s1) + (s2 + s3);
    hist[c] = 0;
    if (c == 0) *mse_acc = 0.0;
}

// ---------------- main: hi-only f16 MFMA argmin + full-scan recheck + fused quant ----------------
// 512 thr = 8 waves; wave wid owns codes [wid*64, wid*64+64).
// Flagged points (coarse top-2 gap < EPS) get an exact fp32 full 512-code scan.
__global__ __launch_bounds__(512) void som_main(const float* __restrict__ x,
                                                const float* __restrict__ w,
                                                const _Float16* __restrict__ wfh,
                                                float* __restrict__ out,
                                                const float* __restrict__ wsq,
                                                int* __restrict__ hist,
                                                double* __restrict__ mse_acc)
{
    alignas(16) __shared__ _Float16 xh[BM * XSTR];   // 33,792 B
    __shared__ float wsq_s[KC];                      // 2 KB
    __shared__ float xsq_s[BM];                      // 256 B
    __shared__ float red_b[8][BM], red_s[8][BM];     // 4 KB
    __shared__ int   red_ib[8][BM], red_is[8][BM];   // 4 KB
    __shared__ int   bidx_s[BM];                     // 256 B
    __shared__ int   flg[BM];                        // 256 B
    __shared__ int   flg_n;

    const int tid  = threadIdx.x;
    const int lane = tid & 63;
    const int wid  = tid >> 6;        // wave 0..7: code group of 64
    const int l15  = lane & 15;
    const int kg   = lane >> 4;
    const int ptBlock = blockIdx.x * BM;

    if (tid == 0) flg_n = 0;

    // ---- stage x tile: hi-f16 in LDS + |x|^2 partials ----
    const float4* xg4 = reinterpret_cast<const float4*>(x);
    #pragma unroll
    for (int it = 0; it < 4; ++it) {
        int u = it * 512 + tid, row = u >> 5, c8 = u & 31;
        float4 a = xg4[(size_t)(ptBlock + row) * 64 + c8 * 2];
        float4 b = xg4[(size_t)(ptBlock + row) * 64 + c8 * 2 + 1];
        h8 hv;
        hv[0] = (_Float16)a.x; hv[1] = (_Float16)a.y;
        hv[2] = (_Float16)a.z; hv[3] = (_Float16)a.w;
        hv[4] = (_Float16)b.x; hv[5] = (_Float16)b.y;
        hv[6] = (_Float16)b.z; hv[7] = (_Float16)b.w;
        *reinterpret_cast<h8*>(&xh[row * XSTR + c8 * 8]) = hv;
        float s = ((fmaf(a.x, a.x, a.y * a.y) + fmaf(a.z, a.z, a.w * a.w))
                 + (fmaf(b.x, b.x, b.y * b.y) + fmaf(b.z, b.z, b.w * b.w)));
        #pragma unroll
        for (int m = 1; m <= 16; m <<= 1) s += __shfl_xor(s, m, 64);
        if ((lane & 31) == 0) xsq_s[row] = s;
    }
    wsq_s[tid] = wsq[tid];            // 512 threads cover K=512
    __syncthreads();

    const int codeBase = wid * 64;
    const int ctg0 = codeBase >> 4;
    const _Float16* __restrict__ pH = wfh + kg * 128 + l15 * 8;

    f32x4 acc[4][4];                  // [rt (code tile)][ct (point tile)]
    #pragma unroll
    for (int rt = 0; rt < 4; ++rt)
        #pragma unroll
        for (int ct = 0; ct < 4; ++ct)
            acc[rt][ct] = (f32x4){0.f, 0.f, 0.f, 0.f};

    #pragma unroll 1
    for (int dsl = 0; dsl < 8; ++dsl) {
        h8 Bh[4];
        #pragma unroll
        for (int ct = 0; ct < 4; ++ct)
            Bh[ct] = *reinterpret_cast<const h8*>(&xh[(ct * 16 + l15) * XSTR + dsl * 32 + kg * 8]);
        #pragma unroll
        for (int rt = 0; rt < 4; ++rt) {
            size_t aoff = ((size_t)((ctg0 + rt) * 8 + dsl)) * 512;
            h8 Ah = *reinterpret_cast<const h8*>(pH + aoff);
            #pragma unroll
            for (int ct = 0; ct < 4; ++ct)
                acc[rt][ct] = __builtin_amdgcn_mfma_f32_16x16x32_f16(Ah, Bh[ct], acc[rt][ct], 0, 0, 0);
        }
    }

    // per-lane top-2 scan, codes ascending in (rt, r)
    float sb[4], ss[4];
    int   ib[4], is2[4];
    #pragma unroll
    for (int ct = 0; ct < 4; ++ct) { sb[ct] = INFINITY; ss[ct] = INFINITY; ib[ct] = 0; is2[ct] = 0; }
    #pragma unroll
    for (int rt = 0; rt < 4; ++rt) {
        int cbase = codeBase + rt * 16 + kg * 4;
        #pragma unroll
        for (int ct = 0; ct < 4; ++ct) {
            #pragma unroll
            for (int r = 0; r < 4; ++r) {
                int cc = cbase + r;
                float d = wsq_s[cc] - 2.f * acc[rt][ct][r];
                if (d < sb[ct] || (d == sb[ct] && cc < ib[ct])) {
                    ss[ct] = sb[ct]; is2[ct] = ib[ct]; sb[ct] = d; ib[ct] = cc;
                } else if (d < ss[ct] || (d == ss[ct] && cc < is2[ct])) {
                    ss[ct] = d; is2[ct] = cc;
                }
            }
        }
    }
    // cross-lane merge over kg groups: masks 16, 32
    #pragma unroll
    for (int ct = 0; ct < 4; ++ct) {
        #pragma unroll
        for (int m = 16; m <= 32; m <<= 1) {
            float ob1 = __shfl_xor(sb[ct], m, 64), ob2 = __shfl_xor(ss[ct], m, 64);
            int   oi1 = __shfl_xor(ib[ct], m, 64), oi2 = __shfl_xor(is2[ct], m, 64);
            merge_top2(sb[ct], ib[ct], ss[ct], is2[ct], ob1, oi1, ob2, oi2);
        }
    }
    if (kg == 0) {
        #pragma unroll
        for (int ct = 0; ct < 4; ++ct) {
            int p = ct * 16 + l15;
            red_b[wid][p] = sb[ct];  red_s[wid][p] = ss[ct];
            red_ib[wid][p] = ib[ct]; red_is[wid][p] = is2[ct];
        }
    }
    __syncthreads();

    // classify: wave 0 merges; safe points finish, near-ties go to the flag list
    if (tid < BM) {
        float b = red_b[0][tid], s = red_s[0][tid];
        int  bi = red_ib[0][tid], si = red_is[0][tid];
        #pragma unroll
        for (int g = 1; g < 8; ++g)
            merge_top2(b, bi, s, si, red_b[g][tid], red_ib[g][tid], red_s[g][tid], red_is[g][tid]);

        float msum = 0.f;
        if (s - b < EPS) {
            int slot = atomicAdd(&flg_n, 1);       // LDS atomic
            flg[slot] = tid;
        } else {
            bidx_s[tid] = bi;
            out[EOFF + ptBlock + tid] = (float)bi;
            atomicAdd(&hist[bi], 1);
            msum = xsq_s[tid] + b;                 // coarse |x-w|^2; err ~1e-2/pt, mse-safe
        }
        #pragma unroll
        for (int m = 32; m; m >>= 1) msum += __shfl_xor(msum, m, 64);
        if (tid == 0) atomicAdd(mse_acc, (double)msum);
    }
    __syncthreads();

    // exact fp32 full-scan recheck for flagged points: one wave per point
    {
        const float4* wg4r = reinterpret_cast<const float4*>(w);
        int F = flg_n;
        for (int fi = wid; fi < F; fi += 8) {
            int p = flg[fi];
            float4 xv = xg4[(size_t)(ptBlock + p) * 64 + lane];  // lane owns dims 4*lane..+3
            float best = INFINITY; int bi = 0;
            #pragma unroll 1
            for (int c = 0; c < KC; ++c) {
                float4 wv = wg4r[(size_t)c * 64 + lane];
                float t = fmaf(xv.x, wv.x, fmaf(xv.y, wv.y, fmaf(xv.z, wv.z, xv.w * wv.w)));
                #pragma unroll
                for (int m = 1; m <= 32; m <<= 1) t += __shfl_xor(t, m, 64);
                float d = wsq_s[c] - 2.f * t;
                if (d < best) { best = d; bi = c; }   // first-index kept on ties
            }
            if (lane == 0) {
                bidx_s[p] = bi;
                out[EOFF + ptBlock + p] = (float)bi;
                atomicAdd(&hist[bi], 1);
                atomicAdd(mse_acc, (double)(xsq_s[p] + best));
            }
        }
    }
    __syncthreads();

    // fused quantized write: wave per row, 1 KB contiguous R/W (L2-hot w rows)
    {
        const float4* wg4 = reinterpret_cast<const float4*>(w);
        float4* q4 = reinterpret_cast<float4*>(out + QOFF);
        #pragma unroll
        for (int r8 = 0; r8 < 8; ++r8) {
            int row = r8 * 8 + wid;
            int cc = bidx_s[row];
            q4[(size_t)(ptBlock + row) * 64 + lane] = wg4[(size_t)cc * 64 + lane];
        }
    }
}

// ---------------- g[j] = sum_k bmat[j,k] * (wsq[k] + wsq[j] - 2 w_j.w_k) ----------------
__global__ __launch_bounds__(256) void som_g(const float* __restrict__ w,
                                             const float* __restrict__ bmat,
                                             const float* __restrict__ wsq,
                                             float* __restrict__ g)
{
    __shared__ float wj[DIM];
    __shared__ float psum[4];
    const int j = blockIdx.x;
    const int tid = threadIdx.x;
    wj[tid] = w[(size_t)j * DIM + tid];
    __syncthreads();
    const float wsqj = wsq[j];
    float sum = 0.f;
    for (int k = tid; k < KC; k += 256) {
        const float* wk = &w[(size_t)k * DIM];
        float d0 = 0.f, d1 = 0.f, d2 = 0.f, d3 = 0.f;
        #pragma unroll 4
        for (int d = 0; d < DIM; d += 4) {
            d0 = fmaf(wj[d + 0], wk[d + 0], d0);
            d1 = fmaf(wj[d + 1], wk[d + 1], d1);
            d2 = fmaf(wj[d + 2], wk[d + 2], d2);
            d3 = fmaf(wj[d + 3], wk[d + 3], d3);
        }
        float dot = (d0 + d1) + (d2 + d3);
        float t = wsq[k] + wsqj - 2.f * dot;
        sum = fmaf(bmat[(size_t)j * KC + k], t, sum);
    }
    #pragma unroll
    for (int m = 32; m; m >>= 1) sum += __shfl_xor(sum, m, 64);
    int lane = tid & 63, wid = tid >> 6;
    if (lane == 0) psum[wid] = sum;
    __syncthreads();
    if (tid == 0) g[j] = (psum[0] + psum[1]) + (psum[2] + psum[3]);
}

// ---------------- final: perplexity + loss ----------------
__global__ __launch_bounds__(512) void som_final(const int* __restrict__ hist,
                                                 const float* __restrict__ g,
                                                 const double* __restrict__ mse_acc,
                                                 float* __restrict__ out)
{
    __shared__ float e_part[8], k_part[8];
    const int tid = threadIdx.x;
    int cnt = hist[tid];
    float p = (float)cnt / (float)NPTS;
    float ent = -p * logf(p + 1e-10f);
    float koh = (float)cnt * g[tid];
    #pragma unroll
    for (int m = 32; m; m >>= 1) {
        ent += __shfl_xor(ent, m, 64);
        koh += __shfl_xor(koh, m, 64);
    }
    int lane = tid & 63, wid = tid >> 6;
    if (lane == 0) { e_part[wid] = ent; k_part[wid] = koh; }
    __syncthreads();
    if (tid == 0) {
        float es = 0.f, ks = 0.f;
        #pragma unroll
        for (int i = 0; i < 8; ++i) { es += e_part[i]; ks += k_part[i]; }
        float mse = (float)(*mse_acc / (double)(NPTS * (size_t)DIM));
        out[0] = fmaf(1.25f, mse, ks / (float)NPTS);
        out[PIDX] = expf(es);
    }
}

extern "C" void kernel_launch(void* const* d_in, const int* in_sizes, int n_in,
                              void* d_out, int out_size, void* d_ws, size_t ws_size,
                              hipStream_t stream) {
    const float* x    = (const float*)d_in[0];
    const float* w    = (const float*)d_in[1];
    const float* bmat = (const float*)d_in[2];
    float* out = (float*)d_out;

    _Float16* wfh = (_Float16*)d_ws;                         // 256 KB
    float*  wsq  = (float*)((char*)d_ws + 262144);
    float*  g    = (float*)((char*)d_ws + 264192);
    int*    hist = (int*)((char*)d_ws + 266240);
    double* mse  = (double*)((char*)d_ws + 268288);

    som_prep <<<2, 256, 0, stream>>>(w, wfh, wsq, hist, mse);
    som_main <<<NBLK, 512, 0, stream>>>(x, w, wfh, out, wsq, hist, mse);
    som_g    <<<KC, 256, 0, stream>>>(w, bmat, wsq, g);
    som_final<<<1, KC, 0, stream>>>(hist, g, mse, out);
}

// Round 13
// 191.001 us; speedup vs baseline: 2.3974x; 2.3974x over previous
//
#include <hip/hip_runtime.h>
#include <hip/hip_bf16.h>
#include <hip/hip_fp16.h>
#include <math.h>

// Problem constants
#define NPTS 65536
#define DIM  256
#define KC   512

// som_main geometry
#define BM    64                  // points per block
#define NBLK  (NPTS / BM)         // 1024 blocks
#define XSTR  264                 // x LDS row stride in halfs (528 B, 16B-aligned)
#define EPS   0.01f               // split-fp16 coarse err ~2e-5 -> huge margin (r9-proven)

// d_out layout (floats): [0]=loss, [1..1+16777216)=quantized, [16777217]=perplexity,
// [16777218..+65536)=enc_idx (as float)
#define QOFF  1
#define PIDX  16777217
#define EOFF  16777218

// d_ws layout:
//   wfh  _Float16[131072]  @ 0        (256 KB)  w hi, dsl-major MFMA fragment order
//   wfl  _Float16[131072]  @ 262144   (256 KB)  w lo
//   wsq  float[512]        @ 524288
//   g    float[512]        @ 526336
//   hist int[512]          @ 528384
//   mse  double            @ 530432
// dsl-major fragment order:
//   off(c,k) = ((k>>5)*32 + (c>>4))*512 + ((k>>3)&3)*128 + (c&15)*8 + (k&7)
// -> K-slice dsl (k in [dsl*32, dsl*32+32)) is one contiguous 32 KB block.

typedef _Float16 h8    __attribute__((ext_vector_type(8)));
typedef float    f32x4 __attribute__((ext_vector_type(4)));

__device__ inline void cvt_split8(float4 a, float4 b, h8& hv, h8& lv) {
    float f[8] = {a.x, a.y, a.z, a.w, b.x, b.y, b.z, b.w};
    #pragma unroll
    for (int i = 0; i < 8; ++i) {
        _Float16 h = (_Float16)f[i];
        hv[i] = h;
        lv[i] = (_Float16)(f[i] - (float)h);
    }
}

// async global->LDS, 16B per lane (dest = wave-uniform base + lane*16)
__device__ inline void gload16(const _Float16* gp, _Float16* lp) {
    __builtin_amdgcn_global_load_lds(
        (const __attribute__((address_space(1))) void*)gp,
        (__attribute__((address_space(3))) void*)lp, 16, 0, 0);
}

// merge top-2 set with another top-2 set; first-index tie-break on best (r5-verified)
__device__ inline void merge_top2(float& b1, int& i1, float& b2, int& i2,
                                  float ob1, int oi1, float ob2, int oi2) {
    bool ow = (ob1 < b1) || (ob1 == b1 && oi1 < i1);
    float lb = ow ? b1 : ob1; int li = ow ? i1 : oi1;
    if (ow) { b1 = ob1; i1 = oi1; }
    float c2 = b2; int ci = i2;
    if (ob2 < c2 || (ob2 == c2 && oi2 < ci)) { c2 = ob2; ci = oi2; }
    if (lb  < c2 || (lb  == c2 && li  < ci)) { c2 = lb;  ci = li;  }
    b2 = c2; i2 = ci;
}

// exact fp32 distance (same accumulation family as the r3-passing kernel)
__device__ inline float exact_dist(const float* __restrict__ xr,
                                   const float* __restrict__ w, int c, float wsqc) {
    const float* wr = w + (size_t)c * DIM;
    float d0 = 0.f, d1 = 0.f, d2 = 0.f, d3 = 0.f;
    #pragma unroll 4
    for (int d = 0; d < DIM; d += 4) {
        d0 = fmaf(xr[d + 0], wr[d + 0], d0);
        d1 = fmaf(xr[d + 1], wr[d + 1], d1);
        d2 = fmaf(xr[d + 2], wr[d + 2], d2);
        d3 = fmaf(xr[d + 3], wr[d + 3], d3);
    }
    return wsqc - 2.f * ((d0 + d1) + (d2 + d3));
}

// ---------------- wsq: |w_k|^2 (exact r3 order) + zero hist/mse ----------------
__global__ __launch_bounds__(256) void som_wsq(const float* __restrict__ w,
                                               float* __restrict__ wsq,
                                               int* __restrict__ hist,
                                               double* __restrict__ mse_acc)
{
    int k = blockIdx.x * 256 + threadIdx.x;   // grid = 2
    const float4* r = reinterpret_cast<const float4*>(w + (size_t)k * DIM);
    float s0 = 0.f, s1 = 0.f, s2 = 0.f, s3 = 0.f;
    #pragma unroll 8
    for (int q = 0; q < DIM / 4; ++q) {
        float4 v = r[q];
        s0 = fmaf(v.x, v.x, s0);
        s1 = fmaf(v.y, v.y, s1);
        s2 = fmaf(v.z, v.z, s2);
        s3 = fmaf(v.w, v.w, s3);
    }
    wsq[k] = (s0 + s1) + (s2 + s3);
    hist[k] = 0;
    if (k == 0) *mse_acc = 0.0;
}

// ---------------- conv: split-f16 conversion of w into dsl-major fragment order ----------------
__global__ __launch_bounds__(256) void som_conv(const float* __restrict__ w,
                                                _Float16* __restrict__ wfh,
                                                _Float16* __restrict__ wfl)
{
    const int tid = threadIdx.x;
    const int row = blockIdx.x * 8 + (tid >> 5);   // code row; grid = 64
    const int g   = tid & 31;                      // h8 unit within row
    const float4* r = reinterpret_cast<const float4*>(w + (size_t)row * DIM);
    float4 a = r[g * 2], b = r[g * 2 + 1];
    h8 hv, lv; cvt_split8(a, b, hv, lv);
    int dsl = g >> 2, kg = g & 3;
    size_t off = ((size_t)(dsl * 32 + (row >> 4))) * 512 + kg * 128 + (row & 15) * 8;
    *reinterpret_cast<h8*>(wfh + off) = hv;
    *reinterpret_cast<h8*>(wfl + off) = lv;
}

// ---------------- main: split-fp16 MFMA argmin, A staged via global_load_lds ----------------
// 512 thr = 8 waves; wave wid owns codes [wid*64, wid*64+64).
// Per dsl: stage 64 KB A-slice (hi+lo) to LDS via global_load_lds -> barrier ->
// 8+8 ds_read_b128 + 48 MFMA per wave -> barrier (m97 2-barrier K-loop pattern).
__global__ __launch_bounds__(512) void som_main(const float* __restrict__ x,
                                                const float* __restrict__ w,
                                                const _Float16* __restrict__ wfh,
                                                const _Float16* __restrict__ wfl,
                                                float* __restrict__ out,
                                                const float* __restrict__ wsq,
                                                int* __restrict__ hist,
                                                double* __restrict__ mse_acc)
{
    alignas(16) __shared__ _Float16 AsH[16384];      // 32 KB: A hi slice (all 512 codes, k-slice 32)
    alignas(16) __shared__ _Float16 AsL[16384];      // 32 KB: A lo slice
    alignas(16) __shared__ _Float16 xh[BM * XSTR];   // 33,792 B
    alignas(16) __shared__ _Float16 xl[BM * XSTR];   // 33,792 B
    __shared__ float wsq_s[KC];                      // 2 KB
    __shared__ float xsq_s[BM];                      // 256 B
    __shared__ float red_b[8][BM], red_s[8][BM];     // 4 KB
    __shared__ int   red_ib[8][BM], red_is[8][BM];   // 4 KB
    __shared__ int   bidx_s[BM];                     // 256 B

    const int tid  = threadIdx.x;
    const int lane = tid & 63;
    const int wid  = tid >> 6;        // wave 0..7: code group of 64
    const int l15  = lane & 15;
    const int kg   = lane >> 4;
    const int ptBlock = blockIdx.x * BM;

    // ---- stage x tile: split to f16 hi/lo in LDS + |x|^2 partials (r9-proven) ----
    const float4* xg4 = reinterpret_cast<const float4*>(x);
    #pragma unroll
    for (int it = 0; it < 4; ++it) {
        int u = it * 512 + tid, row = u >> 5, c8 = u & 31;
        float4 a = xg4[(size_t)(ptBlock + row) * 64 + c8 * 2];
        float4 b = xg4[(size_t)(ptBlock + row) * 64 + c8 * 2 + 1];
        h8 hv, lv; cvt_split8(a, b, hv, lv);
        *reinterpret_cast<h8*>(&xh[row * XSTR + c8 * 8]) = hv;
        *reinterpret_cast<h8*>(&xl[row * XSTR + c8 * 8]) = lv;
        float s = ((fmaf(a.x, a.x, a.y * a.y) + fmaf(a.z, a.z, a.w * a.w))
                 + (fmaf(b.x, b.x, b.y * b.y) + fmaf(b.z, b.z, b.w * b.w)));
        #pragma unroll
        for (int m = 1; m <= 16; m <<= 1) s += __shfl_xor(s, m, 64);
        if ((lane & 31) == 0) xsq_s[row] = s;
    }
    wsq_s[tid] = wsq[tid];            // 512 threads cover K=512

    const int codeBase = wid * 64;
    const int ctg0 = wid * 4;         // first code-tile-group (of 32) for this wave

    f32x4 acc[4][4];                  // [rt (code tile)][ct (point tile)]
    #pragma unroll
    for (int rt = 0; rt < 4; ++rt)
        #pragma unroll
        for (int ct = 0; ct < 4; ++ct)
            acc[rt][ct] = (f32x4){0.f, 0.f, 0.f, 0.f};

    #pragma unroll 1
    for (int dsl = 0; dsl < 8; ++dsl) {
        // stage A slice (hi+lo): 2 x 32 KB, linear global -> linear LDS
        #pragma unroll
        for (int i = 0; i < 4; ++i) {
            size_t goff = (size_t)dsl * 16384 + (size_t)(i * 512 + tid) * 8;
            int loff = (i * 512 + wid * 64) * 8;     // wave-uniform LDS base
            gload16(wfh + goff, &AsH[loff]);
            gload16(wfl + goff, &AsL[loff]);
        }
        __syncthreads();              // drains vmcnt: slice + (iter0) x-tile ready

        h8 Bh[4], Bl[4];
        #pragma unroll
        for (int ct = 0; ct < 4; ++ct) {
            int boff = (ct * 16 + l15) * XSTR + dsl * 32 + kg * 8;
            Bh[ct] = *reinterpret_cast<const h8*>(&xh[boff]);
            Bl[ct] = *reinterpret_cast<const h8*>(&xl[boff]);
        }
        #pragma unroll
        for (int rt = 0; rt < 4; ++rt) {
            int aoff = (ctg0 + rt) * 512 + kg * 128 + l15 * 8;
            h8 Ah = *reinterpret_cast<const h8*>(&AsH[aoff]);
            h8 Al = *reinterpret_cast<const h8*>(&AsL[aoff]);
            #pragma unroll
            for (int ct = 0; ct < 4; ++ct)
                acc[rt][ct] = __builtin_amdgcn_mfma_f32_16x16x32_f16(Ah, Bh[ct], acc[rt][ct], 0, 0, 0);
            #pragma unroll
            for (int ct = 0; ct < 4; ++ct)
                acc[rt][ct] = __builtin_amdgcn_mfma_f32_16x16x32_f16(Al, Bh[ct], acc[rt][ct], 0, 0, 0);
            #pragma unroll
            for (int ct = 0; ct < 4; ++ct)
                acc[rt][ct] = __builtin_amdgcn_mfma_f32_16x16x32_f16(Ah, Bl[ct], acc[rt][ct], 0, 0, 0);
        }
        __syncthreads();              // all waves done reading slice before restage
    }

    // per-lane top-2 scan, codes ascending in (rt, r)  (r9-proven)
    float sb[4], ss[4];
    int   ib[4], is2[4];
    #pragma unroll
    for (int ct = 0; ct < 4; ++ct) { sb[ct] = INFINITY; ss[ct] = INFINITY; ib[ct] = 0; is2[ct] = 0; }
    #pragma unroll
    for (int rt = 0; rt < 4; ++rt) {
        int cbase = codeBase + rt * 16 + kg * 4;
        #pragma unroll
        for (int ct = 0; ct < 4; ++ct) {
            #pragma unroll
            for (int r = 0; r < 4; ++r) {
                int cc = cbase + r;
                float d = wsq_s[cc] - 2.f * acc[rt][ct][r];
                if (d < sb[ct] || (d == sb[ct] && cc < ib[ct])) {
                    ss[ct] = sb[ct]; is2[ct] = ib[ct]; sb[ct] = d; ib[ct] = cc;
                } else if (d < ss[ct] || (d == ss[ct] && cc < is2[ct])) {
                    ss[ct] = d; is2[ct] = cc;
                }
            }
        }
    }
    // cross-lane merge over kg groups: masks 16, 32
    #pragma unroll
    for (int ct = 0; ct < 4; ++ct) {
        #pragma unroll
        for (int m = 16; m <= 32; m <<= 1) {
            float ob1 = __shfl_xor(sb[ct], m, 64), ob2 = __shfl_xor(ss[ct], m, 64);
            int   oi1 = __shfl_xor(ib[ct], m, 64), oi2 = __shfl_xor(is2[ct], m, 64);
            merge_top2(sb[ct], ib[ct], ss[ct], is2[ct], ob1, oi1, ob2, oi2);
        }
    }
    if (kg == 0) {
        #pragma unroll
        for (int ct = 0; ct < 4; ++ct) {
            int p = ct * 16 + l15;
            red_b[wid][p] = sb[ct];  red_s[wid][p] = ss[ct];
            red_ib[wid][p] = ib[ct]; red_is[wid][p] = is2[ct];
        }
    }
    __syncthreads();

    // cross-wave merge + exact top-2 recheck + enc_idx + hist + mse (r9-proven)
    if (tid < BM) {
        float b = red_b[0][tid], s = red_s[0][tid];
        int  bi = red_ib[0][tid], si = red_is[0][tid];
        #pragma unroll
        for (int g = 1; g < 8; ++g)
            merge_top2(b, bi, s, si, red_b[g][tid], red_ib[g][tid], red_s[g][tid], red_is[g][tid]);

        if (s - b < EPS) {            // near-tie: exact fp32 resolve of the two candidates (rare)
            const float* xrp = x + (size_t)(ptBlock + tid) * DIM;
            float d1 = exact_dist(xrp, w, bi, wsq_s[bi]);
            float d2 = exact_dist(xrp, w, si, wsq_s[si]);
            if (d2 < d1 || (d2 == d1 && si < bi)) { bi = si; b = d2; } else { b = d1; }
        }
        bidx_s[tid] = bi;
        out[EOFF + ptBlock + tid] = (float)bi;
        atomicAdd(&hist[bi], 1);

        float msum = xsq_s[tid] + b;  // |x-w|^2 (coarse err ~2e-5, mse-safe)
        #pragma unroll
        for (int m = 32; m; m >>= 1) msum += __shfl_xor(msum, m, 64);
        if (tid == 0) atomicAdd(mse_acc, (double)msum);
    }
    __syncthreads();

    // fused quantized write: wave per row, 1 KB contiguous R/W (L2-hot w rows)
    {
        const float4* wg4 = reinterpret_cast<const float4*>(w);
        float4* q4 = reinterpret_cast<float4*>(out + QOFF);
        #pragma unroll
        for (int r8 = 0; r8 < 8; ++r8) {
            int row = r8 * 8 + wid;
            int cc = bidx_s[row];
            q4[(size_t)(ptBlock + row) * 64 + lane] = wg4[(size_t)cc * 64 + lane];
        }
    }
}

// ---------------- g[j] = sum_k bmat[j,k] * (wsq[k] + wsq[j] - 2 w_j.w_k) ----------------
__global__ __launch_bounds__(256) void som_g(const float* __restrict__ w,
                                             const float* __restrict__ bmat,
                                             const float* __restrict__ wsq,
                                             float* __restrict__ g)
{
    __shared__ float wj[DIM];
    __shared__ float psum[4];
    const int j = blockIdx.x;
    const int tid = threadIdx.x;
    wj[tid] = w[(size_t)j * DIM + tid];
    __syncthreads();
    const float wsqj = wsq[j];
    float sum = 0.f;
    for (int k = tid; k < KC; k += 256) {
        const float* wk = &w[(size_t)k * DIM];
        float d0 = 0.f, d1 = 0.f, d2 = 0.f, d3 = 0.f;
        #pragma unroll 4
        for (int d = 0; d < DIM; d += 4) {
            d0 = fmaf(wj[d + 0], wk[d + 0], d0);
            d1 = fmaf(wj[d + 1], wk[d + 1], d1);
            d2 = fmaf(wj[d + 2], wk[d + 2], d2);
            d3 = fmaf(wj[d + 3], wk[d + 3], d3);
        }
        float dot = (d0 + d1) + (d2 + d3);
        float t = wsq[k] + wsqj - 2.f * dot;
        sum = fmaf(bmat[(size_t)j * KC + k], t, sum);
    }
    #pragma unroll
    for (int m = 32; m; m >>= 1) sum += __shfl_xor(sum, m, 64);
    int lane = tid & 63, wid = tid >> 6;
    if (lane == 0) psum[wid] = sum;
    __syncthreads();
    if (tid == 0) g[j] = (psum[0] + psum[1]) + (psum[2] + psum[3]);
}

// ---------------- final: perplexity + loss ----------------
__global__ __launch_bounds__(512) void som_final(const int* __restrict__ hist,
                                                 const float* __restrict__ g,
                                                 const double* __restrict__ mse_acc,
                                                 float* __restrict__ out)
{
    __shared__ float e_part[8], k_part[8];
    const int tid = threadIdx.x;
    int cnt = hist[tid];
    float p = (float)cnt / (float)NPTS;
    float ent = -p * logf(p + 1e-10f);
    float koh = (float)cnt * g[tid];
    #pragma unroll
    for (int m = 32; m; m >>= 1) {
        ent += __shfl_xor(ent, m, 64);
        koh += __shfl_xor(koh, m, 64);
    }
    int lane = tid & 63, wid = tid >> 6;
    if (lane == 0) { e_part[wid] = ent; k_part[wid] = koh; }
    __syncthreads();
    if (tid == 0) {
        float es = 0.f, ks = 0.f;
        #pragma unroll
        for (int i = 0; i < 8; ++i) { es += e_part[i]; ks += k_part[i]; }
        float mse = (float)(*mse_acc / (double)(NPTS * (size_t)DIM));
        out[0] = fmaf(1.25f, mse, ks / (float)NPTS);
        out[PIDX] = expf(es);
    }
}

extern "C" void kernel_launch(void* const* d_in, const int* in_sizes, int n_in,
                              void* d_out, int out_size, void* d_ws, size_t ws_size,
                              hipStream_t stream) {
    const float* x    = (const float*)d_in[0];
    const float* w    = (const float*)d_in[1];
    const float* bmat = (const float*)d_in[2];
    float* out = (float*)d_out;

    _Float16* wfh = (_Float16*)d_ws;                         // 256 KB
    _Float16* wfl = wfh + 131072;                            // 256 KB
    float*  wsq  = (float*)((char*)d_ws + 524288);
    float*  g    = (float*)((char*)d_ws + 526336);
    int*    hist = (int*)((char*)d_ws + 528384);
    double* mse  = (double*)((char*)d_ws + 530432);

    som_wsq  <<<2, 256, 0, stream>>>(w, wsq, hist, mse);
    som_conv <<<64, 256, 0, stream>>>(w, wfh, wfl);
    som_main <<<NBLK, 512, 0, stream>>>(x, w, wfh, wfl, out, wsq, hist, mse);
    som_g    <<<KC, 256, 0, stream>>>(w, bmat, wsq, g);
    som_final<<<1, KC, 0, stream>>>(hist, g, mse, out);
}

// Round 14
// 164.664 us; speedup vs baseline: 2.7808x; 1.1599x over previous
//
#include <hip/hip_runtime.h>
#include <hip/hip_bf16.h>
#include <hip/hip_fp16.h>
#include <math.h>

// Problem constants
#define NPTS 65536
#define DIM  256
#define KC   512

// som_main geometry
#define BM    128                 // points per block
#define NBLK  (NPTS / BM)         // 512 blocks
#define XSTR  264                 // x LDS row stride in halfs (528 B, 16B-aligned)
#define EPS   0.01f               // split-fp16 coarse err ~2e-5 -> huge margin (r9-proven)

// d_out layout (floats): [0]=loss, [1..1+16777216)=quantized, [16777217]=perplexity,
// [16777218..+65536)=enc_idx (as float)
#define QOFF  1
#define PIDX  16777217
#define EOFF  16777218

// d_ws layout:
//   wfh  _Float16[131072]  @ 0        (256 KB)  w hi, MFMA fragment order (ctg-major, r9)
//   wfl  _Float16[131072]  @ 262144   (256 KB)  w lo
//   wsq  float[512]        @ 524288
//   g    float[512]        @ 526336
//   hist int[512]          @ 528384
//   mse  double            @ 530432
// fragment order: off(c,k) = ((c>>4)*8 + (k>>5))*512 + ((k>>3)&3)*128 + (c&15)*8 + (k&7)

typedef _Float16 h8    __attribute__((ext_vector_type(8)));
typedef float    f32x4 __attribute__((ext_vector_type(4)));

__device__ inline void cvt_split8(float4 a, float4 b, h8& hv, h8& lv) {
    float f[8] = {a.x, a.y, a.z, a.w, b.x, b.y, b.z, b.w};
    #pragma unroll
    for (int i = 0; i < 8; ++i) {
        _Float16 h = (_Float16)f[i];
        hv[i] = h;
        lv[i] = (_Float16)(f[i] - (float)h);
    }
}

// merge top-2 set with another top-2 set; first-index tie-break on best (r5-verified)
__device__ inline void merge_top2(float& b1, int& i1, float& b2, int& i2,
                                  float ob1, int oi1, float ob2, int oi2) {
    bool ow = (ob1 < b1) || (ob1 == b1 && oi1 < i1);
    float lb = ow ? b1 : ob1; int li = ow ? i1 : oi1;
    if (ow) { b1 = ob1; i1 = oi1; }
    float c2 = b2; int ci = i2;
    if (ob2 < c2 || (ob2 == c2 && oi2 < ci)) { c2 = ob2; ci = oi2; }
    if (lb  < c2 || (lb  == c2 && li  < ci)) { c2 = lb;  ci = li;  }
    b2 = c2; i2 = ci;
}

// exact fp32 distance (same accumulation family as the r3-passing kernel)
__device__ inline float exact_dist(const float* __restrict__ xr,
                                   const float* __restrict__ w, int c, float wsqc) {
    const float* wr = w + (size_t)c * DIM;
    float d0 = 0.f, d1 = 0.f, d2 = 0.f, d3 = 0.f;
    #pragma unroll 4
    for (int d = 0; d < DIM; d += 4) {
        d0 = fmaf(xr[d + 0], wr[d + 0], d0);
        d1 = fmaf(xr[d + 1], wr[d + 1], d1);
        d2 = fmaf(xr[d + 2], wr[d + 2], d2);
        d3 = fmaf(xr[d + 3], wr[d + 3], d3);
    }
    return wsqc - 2.f * ((d0 + d1) + (d2 + d3));
}

// ---------------- wsq: |w_k|^2 (exact r3 order) + zero hist/mse ----------------
__global__ __launch_bounds__(256) void som_wsq(const float* __restrict__ w,
                                               float* __restrict__ wsq,
                                               int* __restrict__ hist,
                                               double* __restrict__ mse_acc)
{
    int k = blockIdx.x * 256 + threadIdx.x;   // grid = 2
    const float4* r = reinterpret_cast<const float4*>(w + (size_t)k * DIM);
    float s0 = 0.f, s1 = 0.f, s2 = 0.f, s3 = 0.f;
    #pragma unroll 8
    for (int q = 0; q < DIM / 4; ++q) {
        float4 v = r[q];
        s0 = fmaf(v.x, v.x, s0);
        s1 = fmaf(v.y, v.y, s1);
        s2 = fmaf(v.z, v.z, s2);
        s3 = fmaf(v.w, v.w, s3);
    }
    wsq[k] = (s0 + s1) + (s2 + s3);
    hist[k] = 0;
    if (k == 0) *mse_acc = 0.0;
}

// ---------------- conv: split-f16 conversion of w into fragment order (r9 layout) ----------------
__global__ __launch_bounds__(256) void som_conv(const float* __restrict__ w,
                                                _Float16* __restrict__ wfh,
                                                _Float16* __restrict__ wfl)
{
    const int tid = threadIdx.x;
    const int row = blockIdx.x * 8 + (tid >> 5);   // code row; grid = 64
    const int g   = tid & 31;                      // h8 unit within row
    const float4* r = reinterpret_cast<const float4*>(w + (size_t)row * DIM);
    float4 a = r[g * 2], b = r[g * 2 + 1];
    h8 hv, lv; cvt_split8(a, b, hv, lv);
    int dsl = g >> 2, kg = g & 3;
    int ctg = row >> 4, l15 = row & 15;
    size_t off = (((size_t)(ctg * 8 + dsl)) * 4 + kg) * 128 + l15 * 8;
    *reinterpret_cast<h8*>(wfh + off) = hv;
    *reinterpret_cast<h8*>(wfl + off) = lv;
}

// ---------------- main: split-fp16 MFMA argmin, 16 waves, acc=32, 2 code-passes ----------------
// 1024 thr = 16 waves. Wave wid: pgrp = wid&1 (64 pts), cgrp = wid>>1 (32 codes/pass).
// Per pass (2): codes pass*256 + cgrp*32 + [0,32). acc[2][4] reused across passes;
// running top-2 kept in registers. red/bidx alias dead xh/xl after the MFMA loop.
__global__ __launch_bounds__(1024) void som_main(const float* __restrict__ x,
                                                 const float* __restrict__ w,
                                                 const _Float16* __restrict__ wfh,
                                                 const _Float16* __restrict__ wfl,
                                                 float* __restrict__ out,
                                                 const float* __restrict__ wsq,
                                                 int* __restrict__ hist,
                                                 double* __restrict__ mse_acc)
{
    alignas(16) __shared__ _Float16 xh[BM * XSTR];   // 67,584 B
    alignas(16) __shared__ _Float16 xl[BM * XSTR];   // 67,584 B
    __shared__ float wsq_s[KC];                      // 2 KB
    __shared__ float xsq_s[BM];                      // 512 B
    __shared__ float wsum[2];

    // post-MFMA aliases (xh/xl are dead after the last B-read; barrier-protected)
    float* red_b  = reinterpret_cast<float*>(xh);            // [8][BM]
    float* red_s  = red_b + 8 * BM;                          // [8][BM]
    int*   red_ib = reinterpret_cast<int*>(red_s + 8 * BM);  // [8][BM]
    int*   red_is = red_ib + 8 * BM;                         // [8][BM]
    int*   bidx_s = reinterpret_cast<int*>(xl);              // [BM]

    const int tid  = threadIdx.x;
    const int lane = tid & 63;
    const int wid  = tid >> 6;        // 0..15
    const int l15  = lane & 15;
    const int kg   = lane >> 4;
    const int pgrp = wid & 1;         // point half (64 pts)
    const int cgrp = wid >> 1;        // code group 0..7 (32 codes per pass)
    const int ptBlock = blockIdx.x * BM;

    // ---- stage x tile: split to f16 hi/lo in LDS + |x|^2 partials ----
    const float4* xg4 = reinterpret_cast<const float4*>(x);
    #pragma unroll
    for (int it = 0; it < 4; ++it) {
        int u = it * 1024 + tid, row = u >> 5, c8 = u & 31;   // 4096 h8 units
        float4 a = xg4[(size_t)(ptBlock + row) * 64 + c8 * 2];
        float4 b = xg4[(size_t)(ptBlock + row) * 64 + c8 * 2 + 1];
        h8 hv, lv; cvt_split8(a, b, hv, lv);
        *reinterpret_cast<h8*>(&xh[row * XSTR + c8 * 8]) = hv;
        *reinterpret_cast<h8*>(&xl[row * XSTR + c8 * 8]) = lv;
        float s = ((fmaf(a.x, a.x, a.y * a.y) + fmaf(a.z, a.z, a.w * a.w))
                 + (fmaf(b.x, b.x, b.y * b.y) + fmaf(b.z, b.z, b.w * b.w)));
        #pragma unroll
        for (int m = 1; m <= 16; m <<= 1) s += __shfl_xor(s, m, 64);
        if ((lane & 31) == 0) xsq_s[row] = s;
    }
    if (tid < KC) wsq_s[tid] = wsq[tid];
    __syncthreads();

    // running top-2 per ct (point col = pgrp*64 + ct*16 + l15)
    float sb[4], ss[4];
    int   ib[4], is2[4];
    #pragma unroll
    for (int ct = 0; ct < 4; ++ct) { sb[ct] = INFINITY; ss[ct] = INFINITY; ib[ct] = 0; is2[ct] = 0; }

    #pragma unroll 1
    for (int pass = 0; pass < 2; ++pass) {
        f32x4 acc[2][4];              // [rt (code tile)][ct (point tile)] = 32 regs
        #pragma unroll
        for (int rt = 0; rt < 2; ++rt)
            #pragma unroll
            for (int ct = 0; ct < 4; ++ct)
                acc[rt][ct] = (f32x4){0.f, 0.f, 0.f, 0.f};

        #pragma unroll 1
        for (int dsl = 0; dsl < 8; ++dsl) {
            int boff0 = (pgrp * 64 + l15) * XSTR + dsl * 32 + kg * 8;
            h8 Bh[4];
            #pragma unroll
            for (int ct = 0; ct < 4; ++ct)
                Bh[ct] = *reinterpret_cast<const h8*>(&xh[boff0 + ct * 16 * XSTR]);
            h8 Ah[2], Al[2];
            #pragma unroll
            for (int rt = 0; rt < 2; ++rt) {
                int ctg = pass * 16 + cgrp * 2 + rt;
                size_t aoff = ((size_t)ctg * 8 + dsl) * 512 + kg * 128 + l15 * 8;
                Ah[rt] = *reinterpret_cast<const h8*>(wfh + aoff);
                Al[rt] = *reinterpret_cast<const h8*>(wfl + aoff);
            }
            #pragma unroll
            for (int rt = 0; rt < 2; ++rt)
                #pragma unroll
                for (int ct = 0; ct < 4; ++ct)
                    acc[rt][ct] = __builtin_amdgcn_mfma_f32_16x16x32_f16(Ah[rt], Bh[ct], acc[rt][ct], 0, 0, 0);
            #pragma unroll
            for (int rt = 0; rt < 2; ++rt)
                #pragma unroll
                for (int ct = 0; ct < 4; ++ct)
                    acc[rt][ct] = __builtin_amdgcn_mfma_f32_16x16x32_f16(Al[rt], Bh[ct], acc[rt][ct], 0, 0, 0);
            h8 Bl[4];                 // loaded late so Bh regs can die first
            #pragma unroll
            for (int ct = 0; ct < 4; ++ct)
                Bl[ct] = *reinterpret_cast<const h8*>(&xl[boff0 + ct * 16 * XSTR]);
            #pragma unroll
            for (int rt = 0; rt < 2; ++rt)
                #pragma unroll
                for (int ct = 0; ct < 4; ++ct)
                    acc[rt][ct] = __builtin_amdgcn_mfma_f32_16x16x32_f16(Ah[rt], Bl[ct], acc[rt][ct], 0, 0, 0);
        }

        // in-lane scan into running top-2; codes ascend over (pass, rt, r)
        #pragma unroll
        for (int rt = 0; rt < 2; ++rt) {
            #pragma unroll
            for (int r = 0; r < 4; ++r) {
                int cc = pass * 256 + cgrp * 32 + rt * 16 + kg * 4 + r;
                float wq = wsq_s[cc];
                #pragma unroll
                for (int ct = 0; ct < 4; ++ct) {
                    float d = wq - 2.f * acc[rt][ct][r];
                    if (d < sb[ct] || (d == sb[ct] && cc < ib[ct])) {
                        ss[ct] = sb[ct]; is2[ct] = ib[ct]; sb[ct] = d; ib[ct] = cc;
                    } else if (d < ss[ct] || (d == ss[ct] && cc < is2[ct])) {
                        ss[ct] = d; is2[ct] = cc;
                    }
                }
            }
        }
    }

    // cross-lane merge over kg groups: masks 16, 32
    #pragma unroll
    for (int ct = 0; ct < 4; ++ct) {
        #pragma unroll
        for (int m = 16; m <= 32; m <<= 1) {
            float ob1 = __shfl_xor(sb[ct], m, 64), ob2 = __shfl_xor(ss[ct], m, 64);
            int   oi1 = __shfl_xor(ib[ct], m, 64), oi2 = __shfl_xor(is2[ct], m, 64);
            merge_top2(sb[ct], ib[ct], ss[ct], is2[ct], ob1, oi1, ob2, oi2);
        }
    }
    __syncthreads();                  // all xh/xl reads done -> safe to alias

    if (kg == 0) {
        #pragma unroll
        for (int ct = 0; ct < 4; ++ct) {
            int p = pgrp * 64 + ct * 16 + l15;
            red_b[cgrp * BM + p] = sb[ct];  red_s[cgrp * BM + p] = ss[ct];
            red_ib[cgrp * BM + p] = ib[ct]; red_is[cgrp * BM + p] = is2[ct];
        }
    }
    __syncthreads();

    // cross-group merge + exact top-2 recheck + enc_idx + hist + mse partials
    if (tid < BM) {
        float b = red_b[tid], s = red_s[tid];
        int  bi = red_ib[tid], si = red_is[tid];
        #pragma unroll
        for (int g = 1; g < 8; ++g)
            merge_top2(b, bi, s, si, red_b[g * BM + tid], red_ib[g * BM + tid],
                       red_s[g * BM + tid], red_is[g * BM + tid]);

        if (s - b < EPS) {            // near-tie: exact fp32 resolve of the two candidates (rare)
            const float* xrp = x + (size_t)(ptBlock + tid) * DIM;
            float d1 = exact_dist(xrp, w, bi, wsq_s[bi]);
            float d2 = exact_dist(xrp, w, si, wsq_s[si]);
            if (d2 < d1 || (d2 == d1 && si < bi)) { bi = si; b = d2; } else { b = d1; }
        }
        bidx_s[tid] = bi;
        out[EOFF + ptBlock + tid] = (float)bi;
        atomicAdd(&hist[bi], 1);

        float msum = xsq_s[tid] + b;  // |x-w|^2 (coarse err ~2e-5, mse-safe)
        #pragma unroll
        for (int m = 32; m; m >>= 1) msum += __shfl_xor(msum, m, 64);
        if (lane == 0) wsum[wid] = msum;   // wid in {0,1}
    }
    __syncthreads();
    if (tid == 0) atomicAdd(mse_acc, (double)(wsum[0] + wsum[1]));

    // fused quantized write: wave per row, 1 KB contiguous R/W (L2-hot w rows)
    {
        const float4* wg4 = reinterpret_cast<const float4*>(w);
        float4* q4 = reinterpret_cast<float4*>(out + QOFF);
        #pragma unroll
        for (int r8 = 0; r8 < 8; ++r8) {
            int row = r8 * 16 + wid;
            int cc = bidx_s[row];
            q4[(size_t)(ptBlock + row) * 64 + lane] = wg4[(size_t)cc * 64 + lane];
        }
    }
}

// ---------------- g[j] = sum_k bmat[j,k] * (wsq[k] + wsq[j] - 2 w_j.w_k) ----------------
__global__ __launch_bounds__(256) void som_g(const float* __restrict__ w,
                                             const float* __restrict__ bmat,
                                             const float* __restrict__ wsq,
                                             float* __restrict__ g)
{
    __shared__ float wj[DIM];
    __shared__ float psum[4];
    const int j = blockIdx.x;
    const int tid = threadIdx.x;
    wj[tid] = w[(size_t)j * DIM + tid];
    __syncthreads();
    const float wsqj = wsq[j];
    float sum = 0.f;
    for (int k = tid; k < KC; k += 256) {
        const float* wk = &w[(size_t)k * DIM];
        float d0 = 0.f, d1 = 0.f, d2 = 0.f, d3 = 0.f;
        #pragma unroll 4
        for (int d = 0; d < DIM; d += 4) {
            d0 = fmaf(wj[d + 0], wk[d + 0], d0);
            d1 = fmaf(wj[d + 1], wk[d + 1], d1);
            d2 = fmaf(wj[d + 2], wk[d + 2], d2);
            d3 = fmaf(wj[d + 3], wk[d + 3], d3);
        }
        float dot = (d0 + d1) + (d2 + d3);
        float t = wsq[k] + wsqj - 2.f * dot;
        sum = fmaf(bmat[(size_t)j * KC + k], t, sum);
    }
    #pragma unroll
    for (int m = 32; m; m >>= 1) sum += __shfl_xor(sum, m, 64);
    int lane = tid & 63, wid = tid >> 6;
    if (lane == 0) psum[wid] = sum;
    __syncthreads();
    if (tid == 0) g[j] = (psum[0] + psum[1]) + (psum[2] + psum[3]);
}

// ---------------- final: perplexity + loss ----------------
__global__ __launch_bounds__(512) void som_final(const int* __restrict__ hist,
                                                 const float* __restrict__ g,
                                                 const double* __restrict__ mse_acc,
                                                 float* __restrict__ out)
{
    __shared__ float e_part[8], k_part[8];
    const int tid = threadIdx.x;
    int cnt = hist[tid];
    float p = (float)cnt / (float)NPTS;
    float ent = -p * logf(p + 1e-10f);
    float koh = (float)cnt * g[tid];
    #pragma unroll
    for (int m = 32; m; m >>= 1) {
        ent += __shfl_xor(ent, m, 64);
        koh += __shfl_xor(koh, m, 64);
    }
    int lane = tid & 63, wid = tid >> 6;
    if (lane == 0) { e_part[wid] = ent; k_part[wid] = koh; }
    __syncthreads();
    if (tid == 0) {
        float es = 0.f, ks = 0.f;
        #pragma unroll
        for (int i = 0; i < 8; ++i) { es += e_part[i]; ks += k_part[i]; }
        float mse = (float)(*mse_acc / (double)(NPTS * (size_t)DIM));
        out[0] = fmaf(1.25f, mse, ks / (float)NPTS);
        out[PIDX] = expf(es);
    }
}

extern "C" void kernel_launch(void* const* d_in, const int* in_sizes, int n_in,
                              void* d_out, int out_size, void* d_ws, size_t ws_size,
                              hipStream_t stream) {
    const float* x    = (const float*)d_in[0];
    const float* w    = (const float*)d_in[1];
    const float* bmat = (const float*)d_in[2];
    float* out = (float*)d_out;

    _Float16* wfh = (_Float16*)d_ws;                         // 256 KB
    _Float16* wfl = wfh + 131072;                            // 256 KB
    float*  wsq  = (float*)((char*)d_ws + 524288);
    float*  g    = (float*)((char*)d_ws + 526336);
    int*    hist = (int*)((char*)d_ws + 528384);
    double* mse  = (double*)((char*)d_ws + 530432);

    som_wsq  <<<2, 256, 0, stream>>>(w, wsq, hist, mse);
    som_conv <<<64, 256, 0, stream>>>(w, wfh, wfl);
    som_main <<<NBLK, 1024, 0, stream>>>(x, w, wfh, wfl, out, wsq, hist, mse);
    som_g    <<<KC, 256, 0, stream>>>(w, bmat, wsq, g);
    som_final<<<1, KC, 0, stream>>>(hist, g, mse, out);
}